// Round 1
// baseline (522.516 us; speedup 1.0000x reference)
//
#include <hip/hip_runtime.h>
#include <stdint.h>

// Problem constants: B=4, S=2048, D=1024, H=16, Hd=64, M=B*S=8192.
// All GEMMs are M=8192 (or N=1024 square for weights), K=N=1024.

typedef float f32x4 __attribute__((ext_vector_type(4)));
typedef __bf16 bf16x8 __attribute__((ext_vector_type(8)));
typedef uint32_t u32x4 __attribute__((ext_vector_type(4)));

#define MFMA16(a, b, c) __builtin_amdgcn_mfma_f32_16x16x32_bf16((a), (b), (c), 0, 0, 0)

__device__ __forceinline__ unsigned short f2bf(float f) {
  union { float f; uint32_t u; } c; c.f = f;
  uint32_t u = c.u;
  return (unsigned short)((u + 0x7fffu + ((u >> 16) & 1u)) >> 16);  // RNE
}

// ---------------------------------------------------------------- casts
__global__ __launch_bounds__(256) void cast_x_kernel(const float* __restrict__ in,
                                                     unsigned short* __restrict__ out,
                                                     int n4) {
  int i = blockIdx.x * 256 + threadIdx.x;
  if (i >= n4) return;
  float4 v = ((const float4*)in)[i];
  ushort4 o;
  o.x = f2bf(v.x); o.y = f2bf(v.y); o.z = f2bf(v.z); o.w = f2bf(v.w);
  ((ushort4*)out)[i] = o;
}

// W [1024(k)][1024(n)] fp32 -> Wt [1024(n)][1024(k)] bf16 (so GEMM B-frags are contiguous)
__global__ __launch_bounds__(256) void transpose_cast(const float* __restrict__ W,
                                                      unsigned short* __restrict__ Wt) {
  __shared__ float tile[32][33];
  int k0 = blockIdx.x * 32, n0 = blockIdx.y * 32;
  int tx = threadIdx.x, ty = threadIdx.y;
#pragma unroll
  for (int i = 0; i < 32; i += 8)
    tile[ty + i][tx] = W[(size_t)(k0 + ty + i) * 1024 + n0 + tx];
  __syncthreads();
#pragma unroll
  for (int i = 0; i < 32; i += 8)
    Wt[(size_t)(n0 + ty + i) * 1024 + k0 + tx] = f2bf(tile[tx][ty + i]);
}

// ---------------------------------------------------------------- GEMM
// C[8192,1024] = A[8192,1024] @ Wt^T + bias.  A row-major bf16, Wt is W^T row-major [N][K] bf16.
// MODE 0: out fp32 row-major [M][N].  MODE 1: out bf16 scattered to [B,H,S,Hd].
template <int MODE>
__global__ __launch_bounds__(256) void gemm128(const unsigned short* __restrict__ A,
                                               const unsigned short* __restrict__ Bt,
                                               const float* __restrict__ bias,
                                               void* __restrict__ out) {
  constexpr int Kd = 1024, Nd = 1024;
  __shared__ unsigned short sm[128 * 32 + 32 * 128];  // As (8KB) then Bs (8KB)
  unsigned short* As = sm;
  unsigned short* Bs = sm + 128 * 32;
  auto lds3 = (__attribute__((address_space(3))) char*)sm;

  const int tid = threadIdx.x;
  const int wave = tid >> 6, lane = tid & 63, quad = lane >> 4, l16 = lane & 15;
  const int wm = wave >> 1, wn = wave & 1;
  const int bm = blockIdx.y * 128, bn = blockIdx.x * 128;

  f32x4 acc[4][4] = {};

  for (int k0 = 0; k0 < Kd; k0 += 32) {
    // global -> LDS async staging, 16B/lane, lane-linear layout (no padding allowed)
#pragma unroll
    for (int j = 0; j < 2; ++j) {
      int i = (wave * 2 + j) * 64 + lane;             // 16B-chunk index 0..511
      const unsigned short* ga = A + (size_t)(bm + (i >> 2)) * Kd + k0 + (i & 3) * 8;
      __builtin_amdgcn_global_load_lds(
          (const __attribute__((address_space(1))) void*)ga,
          (__attribute__((address_space(3))) void*)(lds3 + (size_t)(wave * 2 + j) * 1024),
          16, 0, 0);
      const unsigned short* gb = Bt + (size_t)(bn + (i >> 2)) * Kd + k0 + (i & 3) * 8;
      __builtin_amdgcn_global_load_lds(
          (const __attribute__((address_space(1))) void*)gb,
          (__attribute__((address_space(3))) void*)(lds3 + 8192 + (size_t)(wave * 2 + j) * 1024),
          16, 0, 0);
    }
    __syncthreads();  // drains vmcnt before barrier

    bf16x8 af[4], bfv[4];
#pragma unroll
    for (int i = 0; i < 4; ++i)
      af[i] = *(const bf16x8*)(As + (wm * 64 + i * 16 + l16) * 32 + quad * 8);
#pragma unroll
    for (int n = 0; n < 4; ++n)
      bfv[n] = *(const bf16x8*)(Bs + (wn * 64 + n * 16 + l16) * 32 + quad * 8);
#pragma unroll
    for (int i = 0; i < 4; ++i)
#pragma unroll
      for (int n = 0; n < 4; ++n)
        acc[i][n] = MFMA16(af[i], bfv[n], acc[i][n]);
    __syncthreads();
  }

  // epilogue: C/D layout col=lane&15, row=quad*4+reg (m89/m91-verified)
#pragma unroll
  for (int i = 0; i < 4; ++i) {
    const int row0 = bm + wm * 64 + i * 16 + quad * 4;
#pragma unroll
    for (int n = 0; n < 4; ++n) {
      const int col = bn + wn * 64 + n * 16 + l16;
      const float bv = bias[col];
#pragma unroll
      for (int r = 0; r < 4; ++r) {
        float v = acc[i][n][r] + bv;
        if (MODE == 0) {
          ((float*)out)[(size_t)(row0 + r) * Nd + col] = v;
        } else {
          int rr = row0 + r;
          int b = rr >> 11, s = rr & 2047;
          int h = col >> 6, hd = col & 63;
          ((unsigned short*)out)[((size_t)(b * 16 + h) * 2048 + s) * 64 + hd] = f2bf(v);
        }
      }
    }
  }
}

// ---------------------------------------------------------------- flash attention
// Q,K,V bf16 [B,H,S,64]; one block = one (b,h) x 64 q-rows; wave = 16 q-rows.
// scores C-layout -> online softmax (16-lane shuffle reduce) -> P via LDS -> PV.
__global__ __launch_bounds__(256) void attn_kernel(const unsigned short* __restrict__ Q,
                                                   const unsigned short* __restrict__ K,
                                                   const unsigned short* __restrict__ V,
                                                   unsigned short* __restrict__ ctx) {
  const int qt = blockIdx.x;   // 0..31
  const int bh = blockIdx.y;   // 0..63
  const int b = bh >> 4, h = bh & 15;
  const int tid = threadIdx.x;
  const int wave = tid >> 6, lane = tid & 63, quad = lane >> 4, l16 = lane & 15;

  __shared__ unsigned short Ks[64 * 80];    // [key][hd], stride 80 keeps 16B align + fewer conflicts
  __shared__ unsigned short Vts[64 * 80];   // [hd][key]
  __shared__ unsigned short Ps[4 * 16 * 80];  // per-wave P scratch [16][80]

  const size_t hb = (size_t)bh * (2048 * 64);
  const int q0 = qt * 64 + wave * 16;

  // Q A-frags (A[m=lane&15][k=quad*8+j]), k = hd
  bf16x8 qf0 = *(const bf16x8*)(Q + hb + (size_t)(q0 + l16) * 64 + quad * 8);
  bf16x8 qf1 = *(const bf16x8*)(Q + hb + (size_t)(q0 + l16) * 64 + 32 + quad * 8);

  float m_run[4], l_run[4];
  f32x4 o[4] = {};
#pragma unroll
  for (int r = 0; r < 4; ++r) { m_run[r] = -1e30f; l_run[r] = 0.f; }

  for (int kb = 0; kb < 2048; kb += 64) {
    // stage K tile and transposed V tile
#pragma unroll
    for (int c = tid; c < 512; c += 256) {
      int key = c >> 3, col = (c & 7) * 8;
      const size_t goff = hb + (size_t)(kb + key) * 64 + col;
      u32x4 kv = *(const u32x4*)(K + goff);
      *(u32x4*)(Ks + key * 80 + col) = kv;
      u32x4 vv = *(const u32x4*)(V + goff);
#pragma unroll
      for (int j = 0; j < 4; ++j) {
        uint32_t w = vv[j];
        Vts[(col + 2 * j) * 80 + key] = (unsigned short)(w & 0xffff);
        Vts[(col + 2 * j + 1) * 80 + key] = (unsigned short)(w >> 16);
      }
    }
    __syncthreads();

    // scores S = Q@K^T * 1/8 ; B[k=hd][n=key] = K[key][hd]
    f32x4 sc[4];
#pragma unroll
    for (int n = 0; n < 4; ++n) {
      bf16x8 k0f = *(const bf16x8*)(Ks + (n * 16 + l16) * 80 + quad * 8);
      bf16x8 k1f = *(const bf16x8*)(Ks + (n * 16 + l16) * 80 + 32 + quad * 8);
      f32x4 a = {0.f, 0.f, 0.f, 0.f};
      a = MFMA16(qf0, k0f, a);
      a = MFMA16(qf1, k1f, a);
      sc[n] = a * 0.125f;
    }

    // online softmax; row = quad*4 + r lives in the 16 lanes of this quad
#pragma unroll
    for (int r = 0; r < 4; ++r) {
      float mx = fmaxf(fmaxf(sc[0][r], sc[1][r]), fmaxf(sc[2][r], sc[3][r]));
#pragma unroll
      for (int off = 1; off < 16; off <<= 1) mx = fmaxf(mx, __shfl_xor(mx, off, 64));
      float mnew = fmaxf(m_run[r], mx);
      float al = __expf(m_run[r] - mnew);
      float rs = 0.f;
#pragma unroll
      for (int n = 0; n < 4; ++n) {
        float p = __expf(sc[n][r] - mnew);
        sc[n][r] = p;
        rs += p;
      }
#pragma unroll
      for (int off = 1; off < 16; off <<= 1) rs += __shfl_xor(rs, off, 64);
      m_run[r] = mnew;
      l_run[r] = l_run[r] * al + rs;
      o[0][r] *= al; o[1][r] *= al; o[2][r] *= al; o[3][r] *= al;
    }

    // P: C-layout -> LDS -> A-layout (per-wave private region, no barrier needed)
#pragma unroll
    for (int n = 0; n < 4; ++n)
#pragma unroll
      for (int r = 0; r < 4; ++r)
        Ps[wave * 1280 + (quad * 4 + r) * 80 + n * 16 + l16] = f2bf(sc[n][r]);
    asm volatile("s_waitcnt lgkmcnt(0)" ::: "memory");

    // O += P @ V ; B[k=key][n=hd] = Vts[hd][key]
#pragma unroll
    for (int st = 0; st < 2; ++st) {
      bf16x8 pf = *(const bf16x8*)(Ps + wave * 1280 + l16 * 80 + st * 32 + quad * 8);
#pragma unroll
      for (int os = 0; os < 4; ++os) {
        bf16x8 vf = *(const bf16x8*)(Vts + (os * 16 + l16) * 80 + st * 32 + quad * 8);
        o[os] = MFMA16(pf, vf, o[os]);
      }
    }
    __syncthreads();
  }

  // write context bf16 into [B,S,H*Hd] (= GEMM A layout for O-projection)
#pragma unroll
  for (int os = 0; os < 4; ++os)
#pragma unroll
    for (int r = 0; r < 4; ++r) {
      int s = q0 + quad * 4 + r;
      int col = h * 64 + os * 16 + l16;
      ctx[(size_t)(b * 2048 + s) * 1024 + col] = f2bf(o[os][r] / l_run[r]);
    }
}

// ---------------------------------------------------------------- launch
extern "C" void kernel_launch(void* const* d_in, const int* in_sizes, int n_in,
                              void* d_out, int out_size, void* d_ws, size_t ws_size,
                              hipStream_t stream) {
  const float* x  = (const float*)d_in[0];
  const float* Wq = (const float*)d_in[1];
  const float* bq = (const float*)d_in[2];
  const float* Wk = (const float*)d_in[3];
  const float* bk = (const float*)d_in[4];
  const float* Wv = (const float*)d_in[5];
  const float* bv = (const float*)d_in[6];
  const float* Wo = (const float*)d_in[7];
  const float* bo = (const float*)d_in[8];

  unsigned short* ws  = (unsigned short*)d_ws;
  unsigned short* xb  = ws;                   // 8192*1024
  unsigned short* Wqt = ws + 8388608;         // 1024*1024 each
  unsigned short* Wkt = Wqt + 1048576;
  unsigned short* Wvt = Wkt + 1048576;
  unsigned short* Wot = Wvt + 1048576;
  unsigned short* Qb  = Wot + 1048576;        // [B,H,S,Hd] bf16
  unsigned short* Kb  = Qb + 8388608;
  unsigned short* Vb  = Kb + 8388608;
  unsigned short* Cb  = Vb + 8388608;         // context [B,S,1024] bf16
  // total: 92,274,688 bytes of d_ws

  cast_x_kernel<<<8192, 256, 0, stream>>>(x, xb, 2097152);
  dim3 tg(32, 32), tb(32, 8);
  transpose_cast<<<tg, tb, 0, stream>>>(Wq, Wqt);
  transpose_cast<<<tg, tb, 0, stream>>>(Wk, Wkt);
  transpose_cast<<<tg, tb, 0, stream>>>(Wv, Wvt);
  transpose_cast<<<tg, tb, 0, stream>>>(Wo, Wot);

  dim3 gg(8, 64);  // N/128, M/128
  gemm128<1><<<gg, 256, 0, stream>>>(xb, Wqt, bq, Qb);
  gemm128<1><<<gg, 256, 0, stream>>>(xb, Wkt, bk, Kb);
  gemm128<1><<<gg, 256, 0, stream>>>(xb, Wvt, bv, Vb);

  attn_kernel<<<dim3(32, 64), 256, 0, stream>>>(Qb, Kb, Vb, Cb);

  gemm128<0><<<gg, 256, 0, stream>>>(Cb, Wot, bo, d_out);
}

// Round 2
// 331.217 us; speedup vs baseline: 1.5776x; 1.5776x over previous
//
#include <hip/hip_runtime.h>
#include <stdint.h>

// B=4, S=2048, D=1024, H=16, Hd=64, M=8192.
// Pipeline: cast x -> bf16; W^T casts (QKV contiguous); merged QKV GEMM
// (Q pre-scaled by log2e/8); V transpose to [bh][hd][s]; flash attn with
// un-normalized exp2 softmax; O-projection GEMM (fp32 out).

typedef float f32x4 __attribute__((ext_vector_type(4)));
typedef __bf16 bf16x8 __attribute__((ext_vector_type(8)));
typedef uint32_t u32x4 __attribute__((ext_vector_type(4)));

#define MFMA16(a, b, c) __builtin_amdgcn_mfma_f32_16x16x32_bf16((a), (b), (c), 0, 0, 0)

// Q pre-scale: log2(e)/8 so attn does p = exp2(Q'.K) = e^{QK/8} (unnormalized)
#define QSCALE 0.1803368801111204f

__device__ __forceinline__ unsigned short f2bf(float f) {
  union { float f; uint32_t u; } c; c.f = f;
  uint32_t u = c.u;
  return (unsigned short)((u + 0x7fffu + ((u >> 16) & 1u)) >> 16);  // RNE
}

// ---------------------------------------------------------------- casts
__global__ __launch_bounds__(256) void cast_x_kernel(const float* __restrict__ in,
                                                     unsigned short* __restrict__ out,
                                                     int n4) {
  int i = blockIdx.x * 256 + threadIdx.x;
  if (i >= n4) return;
  float4 v = ((const float4*)in)[i];
  ushort4 o;
  o.x = f2bf(v.x); o.y = f2bf(v.y); o.z = f2bf(v.z); o.w = f2bf(v.w);
  ((ushort4*)out)[i] = o;
}

// W [k][n] fp32 -> Wt [n][k] bf16
__global__ __launch_bounds__(256) void transpose_cast(const float* __restrict__ W,
                                                      unsigned short* __restrict__ Wt) {
  __shared__ float tile[32][33];
  int k0 = blockIdx.x * 32, n0 = blockIdx.y * 32;
  int tx = threadIdx.x, ty = threadIdx.y;
#pragma unroll
  for (int i = 0; i < 32; i += 8)
    tile[ty + i][tx] = W[(size_t)(k0 + ty + i) * 1024 + n0 + tx];
  __syncthreads();
#pragma unroll
  for (int i = 0; i < 32; i += 8)
    Wt[(size_t)(n0 + ty + i) * 1024 + k0 + tx] = f2bf(tile[tx][ty + i]);
}

// ---------------------------------------------------------------- GEMM
// MODE 0: O-proj. out fp32 [8192][1024], bias b0.
// MODE 1: merged QKV. Bt = [3072][1024], out = QKV bf16 base (3 x 8388608),
//         scatter to [b,h,s,hd]; Q (mb==0) scaled by QSCALE. biases b0,b1,b2.
template <int MODE>
__global__ __launch_bounds__(256) void gemm128(const unsigned short* __restrict__ A,
                                               const unsigned short* __restrict__ Bt,
                                               const float* __restrict__ b0,
                                               const float* __restrict__ b1,
                                               const float* __restrict__ b2,
                                               void* __restrict__ out) {
  constexpr int Kd = 1024;
  __shared__ unsigned short sm[128 * 32 + 32 * 128];
  unsigned short* As = sm;
  unsigned short* Bs = sm + 128 * 32;
  auto lds3 = (__attribute__((address_space(3))) char*)sm;

  const int tid = threadIdx.x;
  const int wave = tid >> 6, lane = tid & 63, quad = lane >> 4, l16 = lane & 15;
  const int wm = wave >> 1, wn = wave & 1;
  const int bm = blockIdx.y * 128, bn = blockIdx.x * 128;

  f32x4 acc[4][4] = {};

  for (int k0 = 0; k0 < Kd; k0 += 32) {
#pragma unroll
    for (int j = 0; j < 2; ++j) {
      int i = (wave * 2 + j) * 64 + lane;  // 16B-chunk index 0..511
      const unsigned short* ga = A + (size_t)(bm + (i >> 2)) * Kd + k0 + (i & 3) * 8;
      __builtin_amdgcn_global_load_lds(
          (const __attribute__((address_space(1))) void*)ga,
          (__attribute__((address_space(3))) void*)(lds3 + (size_t)(wave * 2 + j) * 1024),
          16, 0, 0);
      const unsigned short* gb = Bt + (size_t)(bn + (i >> 2)) * Kd + k0 + (i & 3) * 8;
      __builtin_amdgcn_global_load_lds(
          (const __attribute__((address_space(1))) void*)gb,
          (__attribute__((address_space(3))) void*)(lds3 + 8192 + (size_t)(wave * 2 + j) * 1024),
          16, 0, 0);
    }
    __syncthreads();

    bf16x8 af[4], bfv[4];
#pragma unroll
    for (int i = 0; i < 4; ++i)
      af[i] = *(const bf16x8*)(As + (wm * 64 + i * 16 + l16) * 32 + quad * 8);
#pragma unroll
    for (int n = 0; n < 4; ++n)
      bfv[n] = *(const bf16x8*)(Bs + (wn * 64 + n * 16 + l16) * 32 + quad * 8);
#pragma unroll
    for (int i = 0; i < 4; ++i)
#pragma unroll
      for (int n = 0; n < 4; ++n)
        acc[i][n] = MFMA16(af[i], bfv[n], acc[i][n]);
    __syncthreads();
  }

  // epilogue: C/D layout col=lane&15, row=quad*4+reg
  const int mb = bn >> 10;  // matrix id for MODE 1 (block never straddles: 1024%128==0)
  const float* bias = (MODE == 0) ? b0 : (mb == 0 ? b0 : (mb == 1 ? b1 : b2));
  const float scale = (MODE == 1 && mb == 0) ? QSCALE : 1.0f;
  unsigned short* oq = (MODE == 1) ? ((unsigned short*)out + (size_t)mb * 8388608u) : nullptr;

#pragma unroll
  for (int i = 0; i < 4; ++i) {
    const int row0 = bm + wm * 64 + i * 16 + quad * 4;
#pragma unroll
    for (int n = 0; n < 4; ++n) {
      const int col = bn + wn * 64 + n * 16 + l16;
      const int cl = col & 1023;
      const float bv = bias[cl];
#pragma unroll
      for (int r = 0; r < 4; ++r) {
        float v = (acc[i][n][r] + bv) * scale;
        if (MODE == 0) {
          ((float*)out)[(size_t)(row0 + r) * 1024 + col] = v;
        } else {
          int rr = row0 + r;
          int b = rr >> 11, s = rr & 2047;
          int h = cl >> 6, hd = cl & 63;
          oq[((size_t)(b * 16 + h) * 2048 + s) * 64 + hd] = f2bf(v);
        }
      }
    }
  }
}

// ---------------------------------------------------------------- V transpose
// Vb [bh][s][64] bf16 -> VtG [bh][64][2048] bf16. 64x64 tiles via u32 LDS (+1 pad).
__global__ __launch_bounds__(256) void transpose_v(const unsigned short* __restrict__ Vb,
                                                   unsigned short* __restrict__ VtG) {
  __shared__ uint32_t t32[64][33];
  const int bh = blockIdx.y, s0 = blockIdx.x * 64;
  const int tid = threadIdx.x;
  const size_t hbase = (size_t)bh * 131072;
#pragma unroll
  for (int it = 0; it < 2; ++it) {
    int c = tid + it * 256;
    int sr = c >> 3, o4 = (c & 7) * 4;
    u32x4 v = *(const u32x4*)(Vb + hbase + (size_t)(s0 + sr) * 64 + o4 * 2);
    t32[sr][o4] = v[0]; t32[sr][o4 + 1] = v[1];
    t32[sr][o4 + 2] = v[2]; t32[sr][o4 + 3] = v[3];
  }
  __syncthreads();
#pragma unroll
  for (int it = 0; it < 2; ++it) {
    int c = tid + it * 256;
    int hd = c >> 3, so = (c & 7) * 8;
    int hc = hd >> 1, sh = (hd & 1) * 16;
    uint32_t w[4];
#pragma unroll
    for (int j = 0; j < 4; ++j) {
      uint32_t lo = t32[so + 2 * j][hc], hi = t32[so + 2 * j + 1][hc];
      w[j] = ((lo >> sh) & 0xffffu) | (((hi >> sh) & 0xffffu) << 16);
    }
    *(u32x4*)(VtG + hbase + (size_t)hd * 2048 + s0 + so) = *(u32x4*)w;
  }
}

// ---------------------------------------------------------------- flash attention
// Q pre-scaled. One block = (b,h) x 128 q-rows; wave = 32 q-rows (2 tiles).
// p = exp2(Q'.K) unnormalized; per-lane partial row sums; single final reduce.
__global__ __launch_bounds__(256) void attn_kernel(const unsigned short* __restrict__ Q,
                                                   const unsigned short* __restrict__ K,
                                                   const unsigned short* __restrict__ Vt,
                                                   unsigned short* __restrict__ ctx) {
  const int bh = blockIdx.y;
  const int tid = threadIdx.x;
  const int wave = tid >> 6, lane = tid & 63, quad = lane >> 4, l16 = lane & 15;

  // stride 72 ushorts = 36 dwords == 4 mod 32 -> 2-way (free) on b128 frag reads
  __shared__ unsigned short Ks[64 * 72];
  __shared__ unsigned short Vts[64 * 72];
  __shared__ unsigned short Ps[4 * 32 * 72];

  const size_t hb = (size_t)bh * 131072;
  const int q0 = blockIdx.x * 128 + wave * 32;

  bf16x8 qf[2][2];
#pragma unroll
  for (int t = 0; t < 2; ++t)
#pragma unroll
    for (int st = 0; st < 2; ++st)
      qf[t][st] = *(const bf16x8*)(Q + hb + (size_t)(q0 + t * 16 + l16) * 64 + st * 32 + quad * 8);

  f32x4 o[2][4] = {};
  float lacc[2][4] = {{0.f, 0.f, 0.f, 0.f}, {0.f, 0.f, 0.f, 0.f}};

  // staging: 4 x 16B chunks/thread (2 K + 2 Vt), register-prefetched
  const int c0 = tid, c1 = tid + 256;
  const unsigned short* gK0 = K + hb + (size_t)(c0 >> 3) * 64 + (c0 & 7) * 8;
  const unsigned short* gK1 = K + hb + (size_t)(c1 >> 3) * 64 + (c1 & 7) * 8;
  const unsigned short* gV0 = Vt + hb + (size_t)(c0 >> 3) * 2048 + (c0 & 7) * 8;
  const unsigned short* gV1 = Vt + hb + (size_t)(c1 >> 3) * 2048 + (c1 & 7) * 8;
  unsigned short* sK0 = Ks + (c0 >> 3) * 72 + (c0 & 7) * 8;
  unsigned short* sK1 = Ks + (c1 >> 3) * 72 + (c1 & 7) * 8;
  unsigned short* sV0 = Vts + (c0 >> 3) * 72 + (c0 & 7) * 8;
  unsigned short* sV1 = Vts + (c1 >> 3) * 72 + (c1 & 7) * 8;

  u32x4 pk0 = *(const u32x4*)gK0, pk1 = *(const u32x4*)gK1;
  u32x4 pv0 = *(const u32x4*)gV0, pv1 = *(const u32x4*)gV1;
  *(u32x4*)sK0 = pk0; *(u32x4*)sK1 = pk1;
  *(u32x4*)sV0 = pv0; *(u32x4*)sV1 = pv1;
  __syncthreads();

  for (int kb = 0; kb < 2048; kb += 64) {
    const bool more = (kb + 64) < 2048;
    if (more) {
      pk0 = *(const u32x4*)(gK0 + (size_t)(kb + 64) * 64);
      pk1 = *(const u32x4*)(gK1 + (size_t)(kb + 64) * 64);
      pv0 = *(const u32x4*)(gV0 + kb + 64);
      pv1 = *(const u32x4*)(gV1 + kb + 64);
    }

    // QK^T: K-frags shared across both q-tiles
    f32x4 sc[2][4];
#pragma unroll
    for (int n = 0; n < 4; ++n) {
      bf16x8 kf0 = *(const bf16x8*)(Ks + (n * 16 + l16) * 72 + quad * 8);
      bf16x8 kf1 = *(const bf16x8*)(Ks + (n * 16 + l16) * 72 + 32 + quad * 8);
#pragma unroll
      for (int t = 0; t < 2; ++t) {
        f32x4 a = {0.f, 0.f, 0.f, 0.f};
        a = MFMA16(qf[t][0], kf0, a);
        a = MFMA16(qf[t][1], kf1, a);
        sc[t][n] = a;
      }
    }

    // p = exp2(score); accumulate lane-partial l; write P (C-layout -> A-layout via LDS)
#pragma unroll
    for (int t = 0; t < 2; ++t)
#pragma unroll
      for (int n = 0; n < 4; ++n)
#pragma unroll
        for (int r = 0; r < 4; ++r) {
          float p = __builtin_amdgcn_exp2f(sc[t][n][r]);
          lacc[t][r] += p;
          Ps[wave * 2304 + (t * 16 + quad * 4 + r) * 72 + n * 16 + l16] = f2bf(p);
        }
    asm volatile("s_waitcnt lgkmcnt(0)" ::: "memory");  // Ps is per-wave private

    // O += P @ V : V-frags shared across both q-tiles
#pragma unroll
    for (int st = 0; st < 2; ++st) {
      bf16x8 pf0 = *(const bf16x8*)(Ps + wave * 2304 + l16 * 72 + st * 32 + quad * 8);
      bf16x8 pf1 = *(const bf16x8*)(Ps + wave * 2304 + (16 + l16) * 72 + st * 32 + quad * 8);
#pragma unroll
      for (int os = 0; os < 4; ++os) {
        bf16x8 vf = *(const bf16x8*)(Vts + (os * 16 + l16) * 72 + st * 32 + quad * 8);
        o[0][os] = MFMA16(pf0, vf, o[0][os]);
        o[1][os] = MFMA16(pf1, vf, o[1][os]);
      }
    }
    __syncthreads();
    if (more) {
      *(u32x4*)sK0 = pk0; *(u32x4*)sK1 = pk1;
      *(u32x4*)sV0 = pv0; *(u32x4*)sV1 = pv1;
    }
    __syncthreads();
  }

  // final: reduce l across the 16 lanes holding each row, normalize, store
  const int b = bh >> 4, h = bh & 15;
#pragma unroll
  for (int t = 0; t < 2; ++t)
#pragma unroll
    for (int r = 0; r < 4; ++r) {
      float l = lacc[t][r];
      l += __shfl_xor(l, 1, 64); l += __shfl_xor(l, 2, 64);
      l += __shfl_xor(l, 4, 64); l += __shfl_xor(l, 8, 64);
      float inv = 1.0f / l;
      int s = q0 + t * 16 + quad * 4 + r;
#pragma unroll
      for (int os = 0; os < 4; ++os)
        ctx[((size_t)(b * 2048 + s)) * 1024 + h * 64 + os * 16 + l16] = f2bf(o[t][os][r] * inv);
    }
}

// ---------------------------------------------------------------- launch
extern "C" void kernel_launch(void* const* d_in, const int* in_sizes, int n_in,
                              void* d_out, int out_size, void* d_ws, size_t ws_size,
                              hipStream_t stream) {
  const float* x  = (const float*)d_in[0];
  const float* Wq = (const float*)d_in[1];
  const float* bq = (const float*)d_in[2];
  const float* Wk = (const float*)d_in[3];
  const float* bk = (const float*)d_in[4];
  const float* Wv = (const float*)d_in[5];
  const float* bv = (const float*)d_in[6];
  const float* Wo = (const float*)d_in[7];
  const float* bo = (const float*)d_in[8];

  unsigned short* ws = (unsigned short*)d_ws;
  unsigned short* xb    = ws;                    // 8388608 (aliased by VtG later)
  unsigned short* Wtall = ws + 8388608;          // 3*1048576 (Wq^T|Wk^T|Wv^T)
  unsigned short* Wot   = Wtall + 3145728;       // 1048576
  unsigned short* Qb    = Wot + 1048576;         // 8388608  [bh][s][hd], pre-scaled
  unsigned short* Kb    = Qb + 8388608;          // 8388608
  unsigned short* Vb    = Kb + 8388608;          // 8388608
  unsigned short* VtG   = xb;                    // alias: xb dead after QKV GEMM
  unsigned short* Cb    = Vb;                    // alias: Vb dead after transpose_v
  // total 75.5 MB

  cast_x_kernel<<<8192, 256, 0, stream>>>(x, xb, 2097152);
  dim3 tg(32, 32), tb(32, 8);
  transpose_cast<<<tg, tb, 0, stream>>>(Wq, Wtall);
  transpose_cast<<<tg, tb, 0, stream>>>(Wk, Wtall + 1048576);
  transpose_cast<<<tg, tb, 0, stream>>>(Wv, Wtall + 2097152);
  transpose_cast<<<tg, tb, 0, stream>>>(Wo, Wot);

  gemm128<1><<<dim3(24, 64), 256, 0, stream>>>(xb, Wtall, bq, bk, bv, Qb);
  transpose_v<<<dim3(32, 64), 256, 0, stream>>>(Vb, VtG);
  attn_kernel<<<dim3(16, 64), 256, 0, stream>>>(Qb, Kb, VtG, Cb);
  gemm128<0><<<dim3(8, 64), 256, 0, stream>>>(Cb, Wot, bo, nullptr, nullptr, d_out);
}

// Round 3
// 276.566 us; speedup vs baseline: 1.8893x; 1.1976x over previous
//
#include <hip/hip_runtime.h>
#include <stdint.h>

// B=4, S=2048, D=1024, H=16, Hd=64, M=8192.
// Pipeline: cast x -> bf16; merged W^T casts; merged QKV GEMM (Q pre-scaled
// by log2e/8); V transpose to [bh][hd][s]; flash attn computing S^T = K@Q^T
// so exp2(scores) form PV A-frags in-register (key-permutation trick, no P
// LDS round-trip); O-projection GEMM (fp32 out).

typedef float f32x4 __attribute__((ext_vector_type(4)));
typedef __bf16 bf16x4 __attribute__((ext_vector_type(4)));
typedef __bf16 bf16x8 __attribute__((ext_vector_type(8)));
typedef uint32_t u32x4 __attribute__((ext_vector_type(4)));

#define MFMA16(a, b, c) __builtin_amdgcn_mfma_f32_16x16x32_bf16((a), (b), (c), 0, 0, 0)

// Q pre-scale: log2(e)/8 so attn does p = exp2(Q'.K) = e^{QK/8} (unnormalized)
#define QSCALE 0.1803368801111204f

__device__ __forceinline__ unsigned short f2bf(float f) {
  union { float f; uint32_t u; } c; c.f = f;
  uint32_t u = c.u;
  return (unsigned short)((u + 0x7fffu + ((u >> 16) & 1u)) >> 16);  // RNE
}

// ---------------------------------------------------------------- casts
__global__ __launch_bounds__(256) void cast_x_kernel(const float* __restrict__ in,
                                                     unsigned short* __restrict__ out,
                                                     int n4) {
  int i = blockIdx.x * 256 + threadIdx.x;
  if (i >= n4) return;
  float4 v = ((const float4*)in)[i];
  ushort4 o;
  o.x = f2bf(v.x); o.y = f2bf(v.y); o.z = f2bf(v.z); o.w = f2bf(v.w);
  ((ushort4*)out)[i] = o;
}

// 4 weights [k][n] fp32 -> Wt [n][k] bf16, z selects matrix; dst contiguous.
__global__ __launch_bounds__(256) void transpose_cast4(const float* __restrict__ W0,
                                                       const float* __restrict__ W1,
                                                       const float* __restrict__ W2,
                                                       const float* __restrict__ W3,
                                                       unsigned short* __restrict__ Wt) {
  __shared__ float tile[32][33];
  const int z = blockIdx.z;
  const float* W = (z == 0) ? W0 : (z == 1) ? W1 : (z == 2) ? W2 : W3;
  unsigned short* dst = Wt + (size_t)z * 1048576;
  int k0 = blockIdx.x * 32, n0 = blockIdx.y * 32;
  int tx = threadIdx.x, ty = threadIdx.y;
#pragma unroll
  for (int i = 0; i < 32; i += 8)
    tile[ty + i][tx] = W[(size_t)(k0 + ty + i) * 1024 + n0 + tx];
  __syncthreads();
#pragma unroll
  for (int i = 0; i < 32; i += 8)
    dst[(size_t)(n0 + ty + i) * 1024 + k0 + tx] = f2bf(tile[tx][ty + i]);
}

// ---------------------------------------------------------------- GEMM
// MODE 0: O-proj. out fp32 [8192][1024], bias b0.
// MODE 1: merged QKV. Bt = [3072][1024], out = QKV bf16 base (3 x 8388608),
//         scatter to [b,h,s,hd]; Q (mb==0) scaled by QSCALE. biases b0,b1,b2.
template <int MODE>
__global__ __launch_bounds__(256) void gemm128(const unsigned short* __restrict__ A,
                                               const unsigned short* __restrict__ Bt,
                                               const float* __restrict__ b0,
                                               const float* __restrict__ b1,
                                               const float* __restrict__ b2,
                                               void* __restrict__ out) {
  constexpr int Kd = 1024;
  __shared__ unsigned short sm[128 * 32 + 32 * 128];
  unsigned short* As = sm;
  unsigned short* Bs = sm + 128 * 32;
  auto lds3 = (__attribute__((address_space(3))) char*)sm;

  const int tid = threadIdx.x;
  const int wave = tid >> 6, lane = tid & 63, quad = lane >> 4, l16 = lane & 15;
  const int wm = wave >> 1, wn = wave & 1;
  const int bm = blockIdx.y * 128, bn = blockIdx.x * 128;

  f32x4 acc[4][4] = {};

  for (int k0 = 0; k0 < Kd; k0 += 32) {
#pragma unroll
    for (int j = 0; j < 2; ++j) {
      int i = (wave * 2 + j) * 64 + lane;  // 16B-chunk index 0..511
      const unsigned short* ga = A + (size_t)(bm + (i >> 2)) * Kd + k0 + (i & 3) * 8;
      __builtin_amdgcn_global_load_lds(
          (const __attribute__((address_space(1))) void*)ga,
          (__attribute__((address_space(3))) void*)(lds3 + (size_t)(wave * 2 + j) * 1024),
          16, 0, 0);
      const unsigned short* gb = Bt + (size_t)(bn + (i >> 2)) * Kd + k0 + (i & 3) * 8;
      __builtin_amdgcn_global_load_lds(
          (const __attribute__((address_space(1))) void*)gb,
          (__attribute__((address_space(3))) void*)(lds3 + 8192 + (size_t)(wave * 2 + j) * 1024),
          16, 0, 0);
    }
    __syncthreads();

    bf16x8 af[4], bfv[4];
#pragma unroll
    for (int i = 0; i < 4; ++i)
      af[i] = *(const bf16x8*)(As + (wm * 64 + i * 16 + l16) * 32 + quad * 8);
#pragma unroll
    for (int n = 0; n < 4; ++n)
      bfv[n] = *(const bf16x8*)(Bs + (wn * 64 + n * 16 + l16) * 32 + quad * 8);
#pragma unroll
    for (int i = 0; i < 4; ++i)
#pragma unroll
      for (int n = 0; n < 4; ++n)
        acc[i][n] = MFMA16(af[i], bfv[n], acc[i][n]);
    __syncthreads();
  }

  // epilogue: C/D layout col=lane&15, row=quad*4+reg
  const int mb = bn >> 10;  // matrix id for MODE 1 (block never straddles: 1024%128==0)
  const float* bias = (MODE == 0) ? b0 : (mb == 0 ? b0 : (mb == 1 ? b1 : b2));
  const float scale = (MODE == 1 && mb == 0) ? QSCALE : 1.0f;
  unsigned short* oq = (MODE == 1) ? ((unsigned short*)out + (size_t)mb * 8388608u) : nullptr;

#pragma unroll
  for (int i = 0; i < 4; ++i) {
    const int row0 = bm + wm * 64 + i * 16 + quad * 4;
#pragma unroll
    for (int n = 0; n < 4; ++n) {
      const int col = bn + wn * 64 + n * 16 + l16;
      const int cl = col & 1023;
      const float bv = bias[cl];
#pragma unroll
      for (int r = 0; r < 4; ++r) {
        float v = (acc[i][n][r] + bv) * scale;
        if (MODE == 0) {
          ((float*)out)[(size_t)(row0 + r) * 1024 + col] = v;
        } else {
          int rr = row0 + r;
          int b = rr >> 11, s = rr & 2047;
          int h = cl >> 6, hd = cl & 63;
          oq[((size_t)(b * 16 + h) * 2048 + s) * 64 + hd] = f2bf(v);
        }
      }
    }
  }
}

// ---------------------------------------------------------------- V transpose
// Vb [bh][s][64] bf16 -> VtG [bh][64][2048] bf16.
__global__ __launch_bounds__(256) void transpose_v(const unsigned short* __restrict__ Vb,
                                                   unsigned short* __restrict__ VtG) {
  __shared__ uint32_t t32[64][33];
  const int bh = blockIdx.y, s0 = blockIdx.x * 64;
  const int tid = threadIdx.x;
  const size_t hbase = (size_t)bh * 131072;
#pragma unroll
  for (int it = 0; it < 2; ++it) {
    int c = tid + it * 256;
    int sr = c >> 3, o4 = (c & 7) * 4;
    u32x4 v = *(const u32x4*)(Vb + hbase + (size_t)(s0 + sr) * 64 + o4 * 2);
    t32[sr][o4] = v[0]; t32[sr][o4 + 1] = v[1];
    t32[sr][o4 + 2] = v[2]; t32[sr][o4 + 3] = v[3];
  }
  __syncthreads();
#pragma unroll
  for (int it = 0; it < 2; ++it) {
    int c = tid + it * 256;
    int hd = c >> 3, so = (c & 7) * 8;
    int hc = hd >> 1, sh = (hd & 1) * 16;
    uint32_t w[4];
#pragma unroll
    for (int j = 0; j < 4; ++j) {
      uint32_t lo = t32[so + 2 * j][hc], hi = t32[so + 2 * j + 1][hc];
      w[j] = ((lo >> sh) & 0xffffu) | (((hi >> sh) & 0xffffu) << 16);
    }
    *(u32x4*)(VtG + hbase + (size_t)hd * 2048 + s0 + so) = *(u32x4*)w;
  }
}

// ---------------------------------------------------------------- flash attention
// Q pre-scaled. Block = (b,h) x 256 q-rows; wave = 64 q-rows (4 subtiles).
// S^T = K(A) @ Q^T(B): C-layout puts col=l16=qrow, so each lane's 16 exp2'd
// scores (keys quad*4+r per subtile) form PV A-frags directly under the key
// permutation sigma(q*8+j) = st*32 + (j>>2)*16 + q*4 + (j&3); V B-frags use
// the same sigma (two contiguous b64 chunks from the Vt tile). No P in LDS.
__global__ __launch_bounds__(256, 2) void attn_kernel(const unsigned short* __restrict__ Q,
                                                      const unsigned short* __restrict__ K,
                                                      const unsigned short* __restrict__ Vt,
                                                      unsigned short* __restrict__ ctx) {
  const int bh = blockIdx.y;
  const int tid = threadIdx.x;
  const int wave = tid >> 6, lane = tid & 63, quad = lane >> 4, l16 = lane & 15;

  // stride 72 ushorts = 36 dwords == 4 mod 32 -> conflict-free-ish frag reads
  // double buffer: [buf][Ks 64*72 | Vts 64*72]
  __shared__ unsigned short sm[2][2 * 64 * 72];

  const size_t hb = (size_t)bh * 131072;
  const int q0 = blockIdx.x * 256 + wave * 64;

  // Q B-frags: B[k=hd][n=qrow]: lane l16 = qrow, k = quad*8+j (+32*st)
  bf16x8 qf[4][2];
#pragma unroll
  for (int qt = 0; qt < 4; ++qt)
#pragma unroll
    for (int st = 0; st < 2; ++st)
      qf[qt][st] = *(const bf16x8*)(Q + hb + (size_t)(q0 + qt * 16 + l16) * 64 + st * 32 + quad * 8);

  f32x4 o[4][4] = {};
  float lacc[4] = {0.f, 0.f, 0.f, 0.f};

  // staging: 4 x 16B chunks/thread (2 K rows-of-keys + 2 Vt rows-of-hd)
  const int c0 = tid, c1 = tid + 256;
  const unsigned short* gK0 = K + hb + (size_t)(c0 >> 3) * 64 + (c0 & 7) * 8;
  const unsigned short* gK1 = K + hb + (size_t)(c1 >> 3) * 64 + (c1 & 7) * 8;
  const unsigned short* gV0 = Vt + hb + (size_t)(c0 >> 3) * 2048 + (c0 & 7) * 8;
  const unsigned short* gV1 = Vt + hb + (size_t)(c1 >> 3) * 2048 + (c1 & 7) * 8;
  const int sKo = (c0 >> 3) * 72 + (c0 & 7) * 8;
  const int sKo1 = (c1 >> 3) * 72 + (c1 & 7) * 8;

  u32x4 pk0 = *(const u32x4*)gK0, pk1 = *(const u32x4*)gK1;
  u32x4 pv0 = *(const u32x4*)gV0, pv1 = *(const u32x4*)gV1;
  {
    unsigned short* s0b = sm[0];
    *(u32x4*)(s0b + sKo) = pk0; *(u32x4*)(s0b + sKo1) = pk1;
    *(u32x4*)(s0b + 4608 + sKo) = pv0; *(u32x4*)(s0b + 4608 + sKo1) = pv1;
  }
  __syncthreads();

  for (int kb = 0; kb < 2048; kb += 64) {
    const int cur = (kb >> 6) & 1;
    const bool more = (kb + 64) < 2048;
    if (more) {
      pk0 = *(const u32x4*)(gK0 + (size_t)(kb + 64) * 64);
      pk1 = *(const u32x4*)(gK1 + (size_t)(kb + 64) * 64);
      pv0 = *(const u32x4*)(gV0 + kb + 64);
      pv1 = *(const u32x4*)(gV1 + kb + 64);
    }
    const unsigned short* Ks = sm[cur];
    const unsigned short* Vts = sm[cur] + 4608;

    // K A-frags: A[m=key][k=hd]: lane l16 = key (per subtile ks), contiguous hd
    bf16x8 kf[4][2];
#pragma unroll
    for (int ks = 0; ks < 4; ++ks)
#pragma unroll
      for (int st = 0; st < 2; ++st)
        kf[ks][st] = *(const bf16x8*)(Ks + (ks * 16 + l16) * 72 + st * 32 + quad * 8);

    // V B-frags under sigma: two b64 chunks (keys st*32+quad*4+{0..3}, +16)
    bf16x8 vf[4][2];
#pragma unroll
    for (int os = 0; os < 4; ++os)
#pragma unroll
      for (int st = 0; st < 2; ++st) {
        const unsigned short* rb = Vts + (os * 16 + l16) * 72 + st * 32 + quad * 4;
        bf16x4 a = *(const bf16x4*)rb;
        bf16x4 b2 = *(const bf16x4*)(rb + 16);
        vf[os][st] = __builtin_shufflevector(a, b2, 0, 1, 2, 3, 4, 5, 6, 7);
      }

#pragma unroll
    for (int qt = 0; qt < 4; ++qt) {
      // S^T tiles: rows = keys (quad*4+r), cols = qrows (l16)
      f32x4 sc[4];
#pragma unroll
      for (int ks = 0; ks < 4; ++ks) {
        f32x4 a = {0.f, 0.f, 0.f, 0.f};
        a = MFMA16(kf[ks][0], qf[qt][0], a);
        a = MFMA16(kf[ks][1], qf[qt][1], a);
        sc[ks] = a;
      }
      // exp2 -> P A-frags in-register; per-lane l partials (all for qrow l16)
      bf16x8 pf[2];
      float ls = 0.f;
#pragma unroll
      for (int ks = 0; ks < 4; ++ks)
#pragma unroll
        for (int r = 0; r < 4; ++r) {
          float p = __builtin_amdgcn_exp2f(sc[ks][r]);
          ls += p;
          pf[ks >> 1][(ks & 1) * 4 + r] = (__bf16)p;
        }
      lacc[qt] += ls;
#pragma unroll
      for (int st = 0; st < 2; ++st)
#pragma unroll
        for (int os = 0; os < 4; ++os)
          o[qt][os] = MFMA16(pf[st], vf[os][st], o[qt][os]);
    }

    if (more) {
      unsigned short* sn = sm[cur ^ 1];
      *(u32x4*)(sn + sKo) = pk0; *(u32x4*)(sn + sKo1) = pk1;
      *(u32x4*)(sn + 4608 + sKo) = pv0; *(u32x4*)(sn + 4608 + sKo1) = pv1;
    }
    __syncthreads();
  }

  // finalize: reduce l across quads (lane's l16 = qrow), redistribute to
  // C-layout rows (quad*4+r), normalize, store.
  const int b = bh >> 4, h = bh & 15;
#pragma unroll
  for (int qt = 0; qt < 4; ++qt) {
    float l = lacc[qt];
    l += __shfl_xor(l, 16, 64);
    l += __shfl_xor(l, 32, 64);
#pragma unroll
    for (int r = 0; r < 4; ++r) {
      float lr = __shfl(l, quad * 4 + r, 16);
      float inv = 1.0f / lr;
      int s = q0 + qt * 16 + quad * 4 + r;
#pragma unroll
      for (int os = 0; os < 4; ++os)
        ctx[((size_t)(b * 2048 + s)) * 1024 + h * 64 + os * 16 + l16] = f2bf(o[qt][os][r] * inv);
    }
  }
}

// ---------------------------------------------------------------- launch
extern "C" void kernel_launch(void* const* d_in, const int* in_sizes, int n_in,
                              void* d_out, int out_size, void* d_ws, size_t ws_size,
                              hipStream_t stream) {
  const float* x  = (const float*)d_in[0];
  const float* Wq = (const float*)d_in[1];
  const float* bq = (const float*)d_in[2];
  const float* Wk = (const float*)d_in[3];
  const float* bk = (const float*)d_in[4];
  const float* Wv = (const float*)d_in[5];
  const float* bv = (const float*)d_in[6];
  const float* Wo = (const float*)d_in[7];
  const float* bo = (const float*)d_in[8];

  unsigned short* ws = (unsigned short*)d_ws;
  unsigned short* xb    = ws;                    // 8388608 (aliased by VtG later)
  unsigned short* Wtall = ws + 8388608;          // 4*1048576 (Wq^T|Wk^T|Wv^T|Wo^T)
  unsigned short* Wot   = Wtall + 3145728;
  unsigned short* Qb    = Wtall + 4194304;       // 8388608  [bh][s][hd], pre-scaled
  unsigned short* Kb    = Qb + 8388608;          // 8388608
  unsigned short* Vb    = Kb + 8388608;          // 8388608
  unsigned short* VtG   = xb;                    // alias: xb dead after QKV GEMM
  unsigned short* Cb    = Vb;                    // alias: Vb dead after transpose_v

  cast_x_kernel<<<8192, 256, 0, stream>>>(x, xb, 2097152);
  transpose_cast4<<<dim3(32, 32, 4), dim3(32, 8), 0, stream>>>(Wq, Wk, Wv, Wo, Wtall);

  gemm128<1><<<dim3(24, 64), 256, 0, stream>>>(xb, Wtall, bq, bk, bv, Qb);
  transpose_v<<<dim3(32, 64), 256, 0, stream>>>(Vb, VtG);
  attn_kernel<<<dim3(8, 64), 256, 0, stream>>>(Qb, Kb, VtG, Cb);
  gemm128<0><<<dim3(8, 64), 256, 0, stream>>>(Cb, Wot, bo, nullptr, nullptr, d_out);
}